// Round 2
// baseline (5260.885 us; speedup 1.0000x reference)
//
#include <hip/hip_runtime.h>
#include <cstdint>
#include <initializer_list>

// Problem constants
#define B_   256   // BATCH
#define N_   256   // NODE_NUM
#define S_   128   // SEQ_LEN
#define Fm1  63    // FEATURE_NUM-1
#define XROW 65    // FEATURE_NUM+1 (x last-dim)
#define H1   512   // HIDDEN/2
#define H2   1024  // HIDDEN
#define FCH  512   // FC_HIDDEN

// ---------------- adjacency normalization ----------------
__global__ void k_dinv(const float* __restrict__ adj, float* __restrict__ dinv) {
    int n = blockIdx.x;
    float s = 0.f;
    for (int m = threadIdx.x; m < N_; m += 64) s += adj[n * N_ + m];
    for (int off = 32; off; off >>= 1) s += __shfl_down(s, off);
    if (threadIdx.x == 0) dinv[n] = rsqrtf(s + 1.0f);
}

__global__ void k_an(const float* __restrict__ adj, const float* __restrict__ dinv,
                     float* __restrict__ An) {
    int i = blockIdx.x * 256 + threadIdx.x;
    int n = i >> 8, m = i & 255;
    float a = adj[i] + (n == m ? 1.f : 0.f);
    An[i] = a * dinv[n] * dinv[m];
}

// ---------------- station-id extraction ----------------
__global__ void k_sid(const float* __restrict__ x, int* __restrict__ sid,
                      int* __restrict__ gsid) {
    int i = blockIdx.x * 256 + threadIdx.x;   // 32768 = B*S
    int b = i >> 7, j = i & 127;
    int s = (int)x[(size_t)b * (S_ * XROW) + j * XROW + (XROW - 2)];
    sid[i] = s;
    if (j == S_ - 1) gsid[b] = s;
}

// ---------------- layer-1 A-gather (batch chunk) ----------------
// T0[n][bi][f] = sum_j An[n, sid[b0+bi,j]] * x[b0+bi,j,f]   (f 0..62; f=63 -> 0)
__global__ void k_t0(const float* __restrict__ x, const int* __restrict__ sid,
                     const float* __restrict__ An, float* __restrict__ T0,
                     int b0, int Bc) {
    int bi = blockIdx.x;
    int gb = b0 + bi;
    __shared__ float sf[S_][64];
    __shared__ int   ss[S_];
    int t = threadIdx.x;   // 256
    for (int idx = t; idx < S_ * 64; idx += 256) {
        int j = idx >> 6, f = idx & 63;
        sf[j][f] = (f < Fm1) ? x[(size_t)gb * (S_ * XROW) + j * XROW + f] : 0.f;
    }
    if (t < S_) ss[t] = sid[gb * S_ + t];
    __syncthreads();
    int tx = t & 63, ty = t >> 6;   // f = tx, node = nc*4 + ty
    for (int nc = 0; nc < N_ / 4; ++nc) {
        int n = nc * 4 + ty;
        float acc = 0.f;
        for (int j = 0; j < S_; ++j) {
            float a = An[n * N_ + ss[j]];        // broadcast across the wave
            if (a != 0.f) acc += a * sf[j][tx];  // uniform branch (~90% skip)
        }
        T0[((size_t)n * Bc + bi) * 64 + tx] = acc;
    }
}

// ---------------- generic fp32 tiled GEMM ----------------
// C[M,N] = act(A[M,K(lda)] @ B[K,N(ldb)] + bias), row-major.
// 64x64 tile, BK=16, 256 threads, 4x4 micro. M,N multiples of 64.
template <int ACT, int HAS_BIAS>
__global__ __launch_bounds__(256) void sgemm(const float* __restrict__ A,
                                             const float* __restrict__ Bm,
                                             const float* __restrict__ bias,
                                             float* __restrict__ C,
                                             int M, int N, int K,
                                             int lda, int ldb, int ldc) {
    __shared__ float As[16][68];   // [k][m], padded
    __shared__ float Bs[16][68];   // [k][n], padded
    int bm = blockIdx.y * 64, bn = blockIdx.x * 64;
    int tid = threadIdx.x;
    int tx = tid & 15, ty = tid >> 4;
    int lrow = tid >> 2, lc4 = (tid & 3) * 4;
    int bkk = tid >> 4, bn4 = (tid & 15) * 4;
    float acc[4][4] = {};
    for (int k0 = 0; k0 < K; k0 += 16) {
        const float* asrc = A + (size_t)(bm + lrow) * lda + k0 + lc4;
#pragma unroll
        for (int i = 0; i < 4; ++i)
            As[lc4 + i][lrow] = (k0 + lc4 + i < K) ? asrc[i] : 0.f;
        {
            int k = k0 + bkk;
            const float* bsrc = Bm + (size_t)k * ldb + bn + bn4;
#pragma unroll
            for (int i = 0; i < 4; ++i)
                Bs[bkk][bn4 + i] = (k < K) ? bsrc[i] : 0.f;
        }
        __syncthreads();
#pragma unroll
        for (int kk = 0; kk < 16; ++kk) {
            float a[4], bb[4];
#pragma unroll
            for (int i = 0; i < 4; ++i) a[i] = As[kk][ty * 4 + i];
#pragma unroll
            for (int j = 0; j < 4; ++j) bb[j] = Bs[kk][tx * 4 + j];
#pragma unroll
            for (int i = 0; i < 4; ++i)
#pragma unroll
                for (int j = 0; j < 4; ++j) acc[i][j] += a[i] * bb[j];
        }
        __syncthreads();
    }
#pragma unroll
    for (int i = 0; i < 4; ++i) {
        int row = bm + ty * 4 + i;
#pragma unroll
        for (int j = 0; j < 4; ++j) {
            int col = bn + tx * 4 + j;
            float v = acc[i][j];
            if (HAS_BIAS) v += bias[col];
            if (ACT == 1) v = fmaxf(v, 0.f);
            C[(size_t)row * ldc + col] = v;
        }
    }
}

// ---------------- layer-3 pruned row-gather (batch chunk) ----------------
// y[b0+bi, h] = sum_m An[gsid[b0+bi], m] * X2[(m,bi), h]
__global__ void k_y(const float* __restrict__ An, const int* __restrict__ gsid,
                    const float* __restrict__ X2, float* __restrict__ y,
                    int b0, int Bc) {
    int bi = blockIdx.x, t = threadIdx.x;   // 256 threads, 2 channels each
    int b = b0 + bi;
    int g = gsid[b];
    float a0 = 0.f, a1 = 0.f;
    for (int m = 0; m < N_; ++m) {
        float a = An[g * N_ + m];   // broadcast
        if (a == 0.f) continue;     // uniform skip (~90%)
        const float* row = X2 + ((size_t)m * Bc + bi) * H1;
        a0 += a * row[t];
        a1 += a * row[t + 256];
    }
    y[(size_t)b * H1 + t] = a0;
    y[(size_t)b * H1 + t + 256] = a1;
}

// ---------------- BatchNorm training stats ----------------
__global__ void k_bnstats(const float* __restrict__ h, float* __restrict__ mv) {
    int c = blockIdx.x * 64 + threadIdx.x;   // 512 channels
    float s = 0.f, s2 = 0.f;
    for (int b = 0; b < B_; ++b) {
        float v = h[(size_t)b * FCH + c];
        s += v; s2 += v * v;
    }
    float mean = s * (1.f / B_);
    float var = s2 * (1.f / B_) - mean * mean;   // biased (torch BN normalization)
    mv[c] = mean;
    mv[FCH + c] = rsqrtf(var + 1e-5f);
}

// ---------------- BN + LeakyReLU + final Linear + sigmoid ----------------
__global__ void k_head(const float* __restrict__ h, const float* __restrict__ mv,
                       const float* __restrict__ gamma, const float* __restrict__ beta,
                       const float* __restrict__ fcW2, const float* __restrict__ fcb2,
                       float* __restrict__ out) {
    int b = blockIdx.x, t = threadIdx.x;   // 512 threads
    float v = h[(size_t)b * FCH + t];
    v = (v - mv[t]) * mv[FCH + t] * gamma[t] + beta[t];
    v = (v >= 0.f) ? v : 0.01f * v;
    float p = v * fcW2[t];
    __shared__ float red[8];
    for (int off = 32; off; off >>= 1) p += __shfl_down(p, off);
    if ((t & 63) == 0) red[t >> 6] = p;
    __syncthreads();
    if (t == 0) {
        float s = fcb2[0];
#pragma unroll
        for (int i = 0; i < 8; ++i) s += red[i];
        out[b] = 1.f / (1.f + expf(-s));
    }
}

static inline size_t align256(size_t x) { return (x + 255) & ~(size_t)255; }

extern "C" void kernel_launch(void* const* d_in, const int* in_sizes, int n_in,
                              void* d_out, int out_size, void* d_ws, size_t ws_size,
                              hipStream_t stream) {
    const float* x     = (const float*)d_in[0];
    const float* adj   = (const float*)d_in[1];
    const float* W1    = (const float*)d_in[2];
    const float* b1    = (const float*)d_in[3];
    const float* W2    = (const float*)d_in[4];
    const float* b2    = (const float*)d_in[5];
    const float* W3    = (const float*)d_in[6];
    const float* b3    = (const float*)d_in[7];
    const float* fcW1  = (const float*)d_in[8];
    const float* fcb1  = (const float*)d_in[9];
    const float* gamma = (const float*)d_in[10];
    const float* beta  = (const float*)d_in[11];
    const float* fcW2  = (const float*)d_in[12];
    const float* fcb2  = (const float*)d_in[13];
    float* out = (float*)d_out;

    // Fixed small buffers
    size_t fixed = 0;
    fixed += align256((size_t)N_ * N_ * 4);        // An
    fixed += align256((size_t)N_ * 4);             // dinv
    fixed += align256((size_t)B_ * S_ * 4);        // sid
    fixed += align256((size_t)B_ * 4);             // gsid
    fixed += align256((size_t)B_ * H1 * 4);        // y
    fixed += align256((size_t)B_ * H2 * 4);        // g
    fixed += align256((size_t)B_ * FCH * 4);       // h
    fixed += align256((size_t)1024 * 4);           // mv

    // Pick largest batch-chunk that fits: need fixed + 2 * (N*Bc*H1*4)
    int Bc = 0;
    for (int c : {64, 32, 16, 8, 4, 2, 1}) {
        size_t need = fixed + 2 * align256((size_t)N_ * c * H1 * 4);
        if (need <= ws_size) { Bc = c; break; }
    }
    if (Bc == 0) return;   // < ~3.6 MB workspace: cannot run

    char* ws = (char*)d_ws;
    size_t off = 0;
    auto alloc = [&](size_t bytes) {
        char* p = ws + off;
        off += align256(bytes);
        return p;
    };
    float* An   = (float*)alloc((size_t)N_ * N_ * 4);
    float* dinv = (float*)alloc((size_t)N_ * 4);
    int*   sid  = (int*)alloc((size_t)B_ * S_ * 4);
    int*   gsid = (int*)alloc((size_t)B_ * 4);
    float* y    = (float*)alloc((size_t)B_ * H1 * 4);
    float* g    = (float*)alloc((size_t)B_ * H2 * 4);
    float* h    = (float*)alloc((size_t)B_ * FCH * 4);
    float* mv   = (float*)alloc((size_t)1024 * 4);
    float* bufA = (float*)alloc((size_t)N_ * Bc * H1 * 4);  // T0_c then T1_c
    float* bufB = (float*)alloc((size_t)N_ * Bc * H1 * 4);  // X1_c then X2_c

    k_dinv<<<N_, 64, 0, stream>>>(adj, dinv);
    k_an<<<N_, 256, 0, stream>>>(adj, dinv, An);
    k_sid<<<(B_ * S_) / 256, 256, 0, stream>>>(x, sid, gsid);

    for (int b0 = 0; b0 < B_; b0 += Bc) {
        // T0_c[n][bi][f]  (uses first N*Bc*64 floats of bufA)
        k_t0<<<Bc, 256, 0, stream>>>(x, sid, An, bufA, b0, Bc);

        // GEMM1: X1_c[(n,bi),h] = relu(T0_c @ W1 + b1)  M=N*Bc, N=512, K=63 (lda=64)
        sgemm<1, 1><<<dim3(H1 / 64, (N_ * Bc) / 64), 256, 0, stream>>>(
            bufA, W1, b1, bufB, N_ * Bc, H1, Fm1, 64, H1, H1);

        // GEMM2: T1_c[n,(bi,h)] = An @ X1_c  M=256, N=Bc*512, K=256
        sgemm<0, 0><<<dim3((Bc * H1) / 64, N_ / 64), 256, 0, stream>>>(
            An, bufB, nullptr, bufA, N_, Bc * H1, N_, N_, Bc * H1, Bc * H1);

        // GEMM3: X2_c[(n,bi),h] = relu(T1_c @ W2 + b2)  M=N*Bc, N=512, K=512
        sgemm<1, 1><<<dim3(H1 / 64, (N_ * Bc) / 64), 256, 0, stream>>>(
            bufA, W2, b2, bufB, N_ * Bc, H1, H1, H1, H1, H1);

        // y[b,h] = An[gsid[b],:] @ X2_c[:,bi,h]
        k_y<<<Bc, 256, 0, stream>>>(An, gsid, bufB, y, b0, Bc);
    }

    // GEMM4: g = relu(y @ W3 + b3)   256 x 1024 x 512
    sgemm<1, 1><<<dim3(H2 / 64, B_ / 64), 256, 0, stream>>>(
        y, W3, b3, g, B_, H2, H1, H1, H2, H2);

    // GEMM5: h = g @ fcW1 + fcb1     256 x 512 x 1024
    sgemm<0, 1><<<dim3(FCH / 64, B_ / 64), 256, 0, stream>>>(
        g, fcW1, fcb1, h, B_, FCH, H2, H2, FCH, FCH);

    k_bnstats<<<FCH / 64, 64, 0, stream>>>(h, mv);
    k_head<<<B_, FCH, 0, stream>>>(h, mv, gamma, beta, fcW2, fcb2, out);
}

// Round 3
// 334.112 us; speedup vs baseline: 15.7459x; 15.7459x over previous
//
#include <hip/hip_runtime.h>
#include <cstdint>
#include <initializer_list>

// Problem constants
#define B_   256   // BATCH
#define N_   256   // NODE_NUM
#define S_   128   // SEQ_LEN
#define Fm1  63    // FEATURE_NUM-1
#define XROW 65    // FEATURE_NUM+1 (x last-dim)
#define H1   512   // HIDDEN/2
#define H2   1024  // HIDDEN
#define FCH  512   // FC_HIDDEN

typedef __attribute__((ext_vector_type(8))) short short8;
typedef __attribute__((ext_vector_type(4))) float f32x4;

__device__ __forceinline__ unsigned short f2bf(float f) {
    union { float f; unsigned u; } v; v.f = f;
    unsigned r = v.u + 0x7FFF + ((v.u >> 16) & 1);   // RNE
    return (unsigned short)(r >> 16);
}
__device__ __forceinline__ float bf2f(unsigned short u) {
    union { unsigned u; float f; } v; v.u = ((unsigned)u) << 16;
    return v.f;
}

// ---------------- adjacency normalization ----------------
__global__ void k_dinv(const float* __restrict__ adj, float* __restrict__ dinv) {
    int n = blockIdx.x;
    float s = 0.f;
    for (int m = threadIdx.x; m < N_; m += 64) s += adj[n * N_ + m];
    for (int off = 32; off; off >>= 1) s += __shfl_down(s, off);
    if (threadIdx.x == 0) dinv[n] = rsqrtf(s + 1.0f);
}

__global__ void k_an(const float* __restrict__ adj, const float* __restrict__ dinv,
                     float* __restrict__ An, unsigned short* __restrict__ Anb) {
    int i = blockIdx.x * 256 + threadIdx.x;
    int n = i >> 8, m = i & 255;
    float a = adj[i] + (n == m ? 1.f : 0.f);
    float v = a * dinv[n] * dinv[m];
    An[i] = v;
    Anb[i] = f2bf(v);
}

// ---------------- station-id extraction ----------------
__global__ void k_sid(const float* __restrict__ x, int* __restrict__ sid,
                      int* __restrict__ gsid) {
    int i = blockIdx.x * 256 + threadIdx.x;   // 32768 = B*S
    int b = i >> 7, j = i & 127;
    int s = (int)x[(size_t)b * (S_ * XROW) + j * XROW + (XROW - 2)];
    sid[i] = s;
    if (j == S_ - 1) gsid[b] = s;
}

// ---------------- fp32 -> bf16 convert with zero-pad tail ----------------
__global__ void k_cvt(const float* __restrict__ in, unsigned short* __restrict__ out,
                      int n_src, int n_tot) {
    int i = blockIdx.x * 256 + threadIdx.x;
    if (i < n_tot) out[i] = (i < n_src) ? f2bf(in[i]) : (unsigned short)0;
}

// ---------------- zero fill (16B granules) ----------------
__global__ void k_zero(uint4* __restrict__ p, int n16) {
    int i = blockIdx.x * 256 + threadIdx.x;
    if (i < n16) p[i] = uint4{0, 0, 0, 0};
}

// ---------------- scatter x -> node-major bf16 Xs[m][bi][64] ----------------
__global__ void k_scatter(const float* __restrict__ x, const int* __restrict__ sid,
                          unsigned short* __restrict__ Xs, int b0, int Bc) {
    int idx = blockIdx.x * 256 + threadIdx.x;    // Bc*S*8 threads
    int f8 = idx & 7;
    int j  = (idx >> 3) & 127;
    int bi = idx >> 10;
    int gb = b0 + bi;
    int s = sid[gb * S_ + j];
    const float* src = x + ((size_t)gb * S_ + j) * XROW + f8 * 8;
    unsigned short o[8];
#pragma unroll
    for (int i = 0; i < 8; ++i) {
        int f = f8 * 8 + i;
        o[i] = (f < Fm1) ? f2bf(src[i]) : (unsigned short)0;
    }
    *(uint4*)(Xs + ((size_t)s * Bc + bi) * 64 + f8 * 8) = *(uint4*)o;
}

// ---------------- bf16 MFMA GEMM ----------------
// C[M,N](bf16) = act(A[M,K](bf16) @ B[K,N](bf16) + bias(f32)), row-major.
// 128x128 tile, 256 threads = 4 waves (2x2), each wave 64x64 (4x4 frags 16x16).
// K-step 32, double-buffered LDS. M,N mult of 128... M>=256 here; N mult of 128;
// K mult of 32.
template <int ACT, int BIAS>
__global__ __launch_bounds__(256) void bgemm(const unsigned short* __restrict__ A,
                                             const unsigned short* __restrict__ B,
                                             const float* __restrict__ bias,
                                             unsigned short* __restrict__ C,
                                             int M, int N, int K,
                                             int lda, int ldb, int ldc) {
    // [buf][kblock][row/col][j]   j = 8 contiguous k-elems of the kblock
    __shared__ unsigned short Abuf[2][4][128][8];
    __shared__ unsigned short Bbuf[2][4][128][8];
    int tid = threadIdx.x;
    int bm = blockIdx.y * 128, bn = blockIdx.x * 128;
    int wid = tid >> 6, lane = tid & 63;
    int wr = wid >> 1, wc = wid & 1;

    int arow = tid >> 1, ahalf = tid & 1;      // A staging
    int bcol = (tid & 63) * 2, bkb = tid >> 6; // B staging (col pair, kblock)

    f32x4 acc[4][4] = {};
    uint4 areg0, areg1;
    unsigned br0[4], br1[4];

    const int nt = K / 32;

    auto gload = [&](int t) {
        int k0 = t * 32;
        const unsigned short* ap = A + (size_t)(bm + arow) * lda + k0 + ahalf * 16;
        areg0 = *(const uint4*)(ap);
        areg1 = *(const uint4*)(ap + 8);
        const unsigned short* bp = B + (size_t)(k0 + bkb * 8) * ldb + bn + bcol;
#pragma unroll
        for (int jj = 0; jj < 4; ++jj) {
            unsigned lo = *(const unsigned*)(bp);            // k = 2jj,   cols c,c+1
            unsigned hi = *(const unsigned*)(bp + ldb);      // k = 2jj+1, cols c,c+1
            br0[jj] = (lo & 0xffffu) | (hi << 16);           // col c,  j=2jj,2jj+1
            br1[jj] = (lo >> 16) | (hi & 0xffff0000u);       // col c+1
            bp += 2 * (size_t)ldb;
        }
    };
    auto swrite = [&](int buf) {
        *(uint4*)(&Abuf[buf][ahalf * 2 + 0][arow][0]) = areg0;
        *(uint4*)(&Abuf[buf][ahalf * 2 + 1][arow][0]) = areg1;
        *(uint4*)(&Bbuf[buf][bkb][bcol][0]) = *(uint4*)br0;
        *(uint4*)(&Bbuf[buf][bkb][bcol + 1][0]) = *(uint4*)br1;
    };

    gload(0);
    swrite(0);
    __syncthreads();
    for (int t = 0; t < nt; ++t) {
        if (t + 1 < nt) gload(t + 1);
        int buf = t & 1;
        int kb = lane >> 4, lr = lane & 15;
        short8 af[4], bfr[4];
#pragma unroll
        for (int i = 0; i < 4; ++i)
            af[i] = *(const short8*)(&Abuf[buf][kb][wr * 64 + i * 16 + lr][0]);
#pragma unroll
        for (int j = 0; j < 4; ++j)
            bfr[j] = *(const short8*)(&Bbuf[buf][kb][wc * 64 + j * 16 + lr][0]);
#pragma unroll
        for (int i = 0; i < 4; ++i)
#pragma unroll
            for (int j = 0; j < 4; ++j)
                acc[i][j] = __builtin_amdgcn_mfma_f32_16x16x32_bf16(
                    af[i], bfr[j], acc[i][j], 0, 0, 0);
        if (t + 1 < nt) swrite(buf ^ 1);
        __syncthreads();
    }
    // epilogue: C/D layout col=lane&15, row=(lane>>4)*4+reg
    int lr = lane & 15, rg = lane >> 4;
#pragma unroll
    for (int j = 0; j < 4; ++j) {
        int col = bn + wc * 64 + j * 16 + lr;
        float bv = BIAS ? bias[col] : 0.f;
#pragma unroll
        for (int i = 0; i < 4; ++i) {
            int row0 = bm + wr * 64 + i * 16 + rg * 4;
#pragma unroll
            for (int r = 0; r < 4; ++r) {
                float v = acc[i][j][r] + bv;
                if (ACT) v = fmaxf(v, 0.f);
                C[(size_t)(row0 + r) * ldc + col] = f2bf(v);
            }
        }
    }
}

// ---------------- generic fp32 tiled GEMM (small tail GEMMs) ----------------
template <int ACT, int HAS_BIAS>
__global__ __launch_bounds__(256) void sgemm(const float* __restrict__ A,
                                             const float* __restrict__ Bm,
                                             const float* __restrict__ bias,
                                             float* __restrict__ C,
                                             int M, int N, int K,
                                             int lda, int ldb, int ldc) {
    __shared__ float As[16][68];
    __shared__ float Bs[16][68];
    int bm = blockIdx.y * 64, bn = blockIdx.x * 64;
    int tid = threadIdx.x;
    int tx = tid & 15, ty = tid >> 4;
    int lrow = tid >> 2, lc4 = (tid & 3) * 4;
    int bkk = tid >> 4, bn4 = (tid & 15) * 4;
    float acc[4][4] = {};
    for (int k0 = 0; k0 < K; k0 += 16) {
        const float* asrc = A + (size_t)(bm + lrow) * lda + k0 + lc4;
#pragma unroll
        for (int i = 0; i < 4; ++i)
            As[lc4 + i][lrow] = (k0 + lc4 + i < K) ? asrc[i] : 0.f;
        {
            int k = k0 + bkk;
            const float* bsrc = Bm + (size_t)k * ldb + bn + bn4;
#pragma unroll
            for (int i = 0; i < 4; ++i)
                Bs[bkk][bn4 + i] = (k < K) ? bsrc[i] : 0.f;
        }
        __syncthreads();
#pragma unroll
        for (int kk = 0; kk < 16; ++kk) {
            float a[4], bb[4];
#pragma unroll
            for (int i = 0; i < 4; ++i) a[i] = As[kk][ty * 4 + i];
#pragma unroll
            for (int j = 0; j < 4; ++j) bb[j] = Bs[kk][tx * 4 + j];
#pragma unroll
            for (int i = 0; i < 4; ++i)
#pragma unroll
                for (int j = 0; j < 4; ++j) acc[i][j] += a[i] * bb[j];
        }
        __syncthreads();
    }
#pragma unroll
    for (int i = 0; i < 4; ++i) {
        int row = bm + ty * 4 + i;
#pragma unroll
        for (int j = 0; j < 4; ++j) {
            int col = bn + tx * 4 + j;
            float v = acc[i][j];
            if (HAS_BIAS) v += bias[col];
            if (ACT == 1) v = fmaxf(v, 0.f);
            C[(size_t)row * ldc + col] = v;
        }
    }
}

// ---------------- layer-3 pruned row-gather (bf16 in, f32 out) ----------------
__global__ void k_y(const float* __restrict__ An, const int* __restrict__ gsid,
                    const unsigned short* __restrict__ X2, float* __restrict__ y,
                    int b0, int Bc) {
    int bi = blockIdx.x, t = threadIdx.x;   // 256 threads, 2 channels each
    int b = b0 + bi;
    int g = gsid[b];
    float a0 = 0.f, a1 = 0.f;
    for (int m = 0; m < N_; ++m) {
        float a = An[g * N_ + m];   // broadcast
        if (a == 0.f) continue;     // uniform skip (~90%)
        const unsigned short* row = X2 + ((size_t)m * Bc + bi) * H1;
        a0 += a * bf2f(row[t]);
        a1 += a * bf2f(row[t + 256]);
    }
    y[(size_t)b * H1 + t] = a0;
    y[(size_t)b * H1 + t + 256] = a1;
}

// ---------------- BatchNorm training stats ----------------
__global__ void k_bnstats(const float* __restrict__ h, float* __restrict__ mv) {
    int c = blockIdx.x * 64 + threadIdx.x;   // 512 channels
    float s = 0.f, s2 = 0.f;
    for (int b = 0; b < B_; ++b) {
        float v = h[(size_t)b * FCH + c];
        s += v; s2 += v * v;
    }
    float mean = s * (1.f / B_);
    float var = s2 * (1.f / B_) - mean * mean;
    mv[c] = mean;
    mv[FCH + c] = rsqrtf(var + 1e-5f);
}

// ---------------- BN + LeakyReLU + final Linear + sigmoid ----------------
__global__ void k_head(const float* __restrict__ h, const float* __restrict__ mv,
                       const float* __restrict__ gamma, const float* __restrict__ beta,
                       const float* __restrict__ fcW2, const float* __restrict__ fcb2,
                       float* __restrict__ out) {
    int b = blockIdx.x, t = threadIdx.x;   // 512 threads
    float v = h[(size_t)b * FCH + t];
    v = (v - mv[t]) * mv[FCH + t] * gamma[t] + beta[t];
    v = (v >= 0.f) ? v : 0.01f * v;
    float p = v * fcW2[t];
    __shared__ float red[8];
    for (int off = 32; off; off >>= 1) p += __shfl_down(p, off);
    if ((t & 63) == 0) red[t >> 6] = p;
    __syncthreads();
    if (t == 0) {
        float s = fcb2[0];
#pragma unroll
        for (int i = 0; i < 8; ++i) s += red[i];
        out[b] = 1.f / (1.f + expf(-s));
    }
}

static inline size_t align256(size_t x) { return (x + 255) & ~(size_t)255; }

extern "C" void kernel_launch(void* const* d_in, const int* in_sizes, int n_in,
                              void* d_out, int out_size, void* d_ws, size_t ws_size,
                              hipStream_t stream) {
    const float* x     = (const float*)d_in[0];
    const float* adj   = (const float*)d_in[1];
    const float* W1    = (const float*)d_in[2];
    const float* b1    = (const float*)d_in[3];
    const float* W2    = (const float*)d_in[4];
    const float* b2    = (const float*)d_in[5];
    const float* W3    = (const float*)d_in[6];
    const float* b3    = (const float*)d_in[7];
    const float* fcW1  = (const float*)d_in[8];
    const float* fcb1  = (const float*)d_in[9];
    const float* gamma = (const float*)d_in[10];
    const float* beta  = (const float*)d_in[11];
    const float* fcW2  = (const float*)d_in[12];
    const float* fcb2  = (const float*)d_in[13];
    float* out = (float*)d_out;

    // Fixed buffers
    size_t fixed = 0;
    fixed += align256((size_t)N_ * N_ * 4);        // An f32
    fixed += align256((size_t)N_ * N_ * 2);        // An bf16
    fixed += align256((size_t)N_ * 4);             // dinv
    fixed += align256((size_t)B_ * S_ * 4);        // sid
    fixed += align256((size_t)B_ * 4);             // gsid
    fixed += align256((size_t)64 * H1 * 2);        // W1b (padded 64 rows)
    fixed += align256((size_t)H1 * H1 * 2);        // W2b
    fixed += align256((size_t)B_ * H1 * 4);        // y
    fixed += align256((size_t)B_ * H2 * 4);        // g
    fixed += align256((size_t)B_ * FCH * 4);       // h
    fixed += align256((size_t)1024 * 4);           // mv

    // chunk buffers: 2 x (N * Bc * H1 bf16)
    int Bc = 0;
    for (int c : {256, 128, 64, 32, 16, 8, 4, 2}) {
        size_t need = fixed + 2 * align256((size_t)N_ * c * H1 * 2);
        if (need <= ws_size) { Bc = c; break; }
    }
    if (Bc == 0) return;

    char* ws = (char*)d_ws;
    size_t off = 0;
    auto alloc = [&](size_t bytes) { char* p = ws + off; off += align256(bytes); return p; };
    float*          An   = (float*)alloc((size_t)N_ * N_ * 4);
    unsigned short* Anb  = (unsigned short*)alloc((size_t)N_ * N_ * 2);
    float*          dinv = (float*)alloc((size_t)N_ * 4);
    int*            sid  = (int*)alloc((size_t)B_ * S_ * 4);
    int*            gsid = (int*)alloc((size_t)B_ * 4);
    unsigned short* W1b  = (unsigned short*)alloc((size_t)64 * H1 * 2);
    unsigned short* W2b  = (unsigned short*)alloc((size_t)H1 * H1 * 2);
    float*          y    = (float*)alloc((size_t)B_ * H1 * 4);
    float*          g    = (float*)alloc((size_t)B_ * H2 * 4);
    float*          h    = (float*)alloc((size_t)B_ * FCH * 4);
    float*          mv   = (float*)alloc((size_t)1024 * 4);
    unsigned short* bufP = (unsigned short*)alloc((size_t)N_ * Bc * H1 * 2); // Xs, X1, X2
    unsigned short* bufQ = (unsigned short*)alloc((size_t)N_ * Bc * H1 * 2); // T0, T1

    k_dinv<<<N_, 64, 0, stream>>>(adj, dinv);
    k_an<<<N_, 256, 0, stream>>>(adj, dinv, An, Anb);
    k_sid<<<(B_ * S_) / 256, 256, 0, stream>>>(x, sid, gsid);
    k_cvt<<<(64 * H1) / 256, 256, 0, stream>>>(W1, W1b, Fm1 * H1, 64 * H1);
    k_cvt<<<(H1 * H1) / 256, 256, 0, stream>>>(W2, W2b, H1 * H1, H1 * H1);

    for (int b0 = 0; b0 < B_; b0 += Bc) {
        // zero + scatter Xs[m][bi][64] (bf16) into bufP
        int n16 = (N_ * Bc * 64) / 8;   // 16B granules
        k_zero<<<(n16 + 255) / 256, 256, 0, stream>>>((uint4*)bufP, n16);
        k_scatter<<<(Bc * S_ * 8) / 256, 256, 0, stream>>>(x, sid, bufP, b0, Bc);

        // GEMM0: T0 = An @ Xs          M=256, N=Bc*64, K=256
        bgemm<0, 0><<<dim3((Bc * 64) / 128, 2), 256, 0, stream>>>(
            Anb, bufP, nullptr, bufQ, N_, Bc * 64, N_, N_, Bc * 64, Bc * 64);

        // GEMM1: X1 = relu(T0 @ W1 + b1)   M=N*Bc, N=512, K=64 (padded)
        bgemm<1, 1><<<dim3(H1 / 128, (N_ * Bc) / 128), 256, 0, stream>>>(
            bufQ, W1b, b1, bufP, N_ * Bc, H1, 64, 64, H1, H1);

        // GEMM2: T1 = An @ X1          M=256, N=Bc*512, K=256
        bgemm<0, 0><<<dim3((Bc * H1) / 128, 2), 256, 0, stream>>>(
            Anb, bufP, nullptr, bufQ, N_, Bc * H1, N_, N_, Bc * H1, Bc * H1);

        // GEMM3: X2 = relu(T1 @ W2 + b2)   M=N*Bc, N=512, K=512
        bgemm<1, 1><<<dim3(H1 / 128, (N_ * Bc) / 128), 256, 0, stream>>>(
            bufQ, W2b, b2, bufP, N_ * Bc, H1, H1, H1, H1, H1);

        // y[b,h] = An[gsid[b],:] @ X2[:,bi,h]
        k_y<<<Bc, 256, 0, stream>>>(An, gsid, bufP, y, b0, Bc);
    }

    // GEMM4: g = relu(y @ W3 + b3)   256 x 1024 x 512
    sgemm<1, 1><<<dim3(H2 / 64, B_ / 64), 256, 0, stream>>>(
        y, W3, b3, g, B_, H2, H1, H1, H2, H2);

    // GEMM5: h = g @ fcW1 + fcb1     256 x 512 x 1024
    sgemm<0, 1><<<dim3(FCH / 64, B_ / 64), 256, 0, stream>>>(
        g, fcW1, fcb1, h, B_, FCH, H2, H2, FCH, FCH);

    k_bnstats<<<FCH / 64, 64, 0, stream>>>(h, mv);
    k_head<<<B_, FCH, 0, stream>>>(h, mv, gamma, beta, fcW2, fcb2, out);
}

// Round 4
// 233.808 us; speedup vs baseline: 22.5008x; 1.4290x over previous
//
#include <hip/hip_runtime.h>
#include <cstdint>
#include <initializer_list>

// Problem constants
#define B_   256   // BATCH
#define N_   256   // NODE_NUM
#define S_   128   // SEQ_LEN
#define Fm1  63    // FEATURE_NUM-1
#define XROW 65    // FEATURE_NUM+1 (x last-dim)
#define H1   512   // HIDDEN/2
#define H2   1024  // HIDDEN
#define FCH  512   // FC_HIDDEN

typedef __attribute__((ext_vector_type(8))) short short8;
typedef __attribute__((ext_vector_type(4))) float f32x4;

__device__ __forceinline__ unsigned short f2bf(float f) {
    union { float f; unsigned u; } v; v.f = f;
    unsigned r = v.u + 0x7FFF + ((v.u >> 16) & 1);   // RNE
    return (unsigned short)(r >> 16);
}
__device__ __forceinline__ float bf2f(unsigned short u) {
    union { unsigned u; float f; } v; v.u = ((unsigned)u) << 16;
    return v.f;
}

// ---------------- adjacency normalization ----------------
__global__ void k_dinv(const float* __restrict__ adj, float* __restrict__ dinv) {
    int n = blockIdx.x;
    float s = 0.f;
    for (int m = threadIdx.x; m < N_; m += 64) s += adj[n * N_ + m];
    for (int off = 32; off; off >>= 1) s += __shfl_down(s, off);
    if (threadIdx.x == 0) dinv[n] = rsqrtf(s + 1.0f);
}

__global__ void k_an(const float* __restrict__ adj, const float* __restrict__ dinv,
                     float* __restrict__ An, unsigned short* __restrict__ Anb) {
    int i = blockIdx.x * 256 + threadIdx.x;
    int n = i >> 8, m = i & 255;
    float a = adj[i] + (n == m ? 1.f : 0.f);
    float v = a * dinv[n] * dinv[m];
    An[i] = v;
    Anb[i] = f2bf(v);
}

// ---------------- station-id extraction ----------------
__global__ void k_sid(const float* __restrict__ x, int* __restrict__ sid,
                      int* __restrict__ gsid) {
    int i = blockIdx.x * 256 + threadIdx.x;   // 32768 = B*S
    int b = i >> 7, j = i & 127;
    int s = (int)x[(size_t)b * (S_ * XROW) + j * XROW + (XROW - 2)];
    sid[i] = s;
    if (j == S_ - 1) gsid[b] = s;
}

// ---------------- fp32 -> bf16 convert with zero-pad tail ----------------
__global__ void k_cvt(const float* __restrict__ in, unsigned short* __restrict__ out,
                      int n_src, int n_tot) {
    int i = blockIdx.x * 256 + threadIdx.x;
    if (i < n_tot) out[i] = (i < n_src) ? f2bf(in[i]) : (unsigned short)0;
}

// ---------------- zero fill (16B granules) ----------------
__global__ void k_zero(uint4* __restrict__ p, int n16) {
    int i = blockIdx.x * 256 + threadIdx.x;
    if (i < n16) p[i] = uint4{0, 0, 0, 0};
}

// ---------------- scatter x -> node-major bf16 Xs[m][bi][64] ----------------
__global__ void k_scatter(const float* __restrict__ x, const int* __restrict__ sid,
                          unsigned short* __restrict__ Xs, int b0, int Bc) {
    int idx = blockIdx.x * 256 + threadIdx.x;    // Bc*S*8 threads
    int f8 = idx & 7;
    int j  = (idx >> 3) & 127;
    int bi = idx >> 10;
    int gb = b0 + bi;
    int s = sid[gb * S_ + j];
    const float* src = x + ((size_t)gb * S_ + j) * XROW + f8 * 8;
    unsigned short o[8];
#pragma unroll
    for (int i = 0; i < 8; ++i) {
        int f = f8 * 8 + i;
        o[i] = (f < Fm1) ? f2bf(src[i]) : (unsigned short)0;
    }
    *(uint4*)(Xs + ((size_t)s * Bc + bi) * 64 + f8 * 8) = *(uint4*)o;
}

// ---------------- bf16 MFMA GEMM ----------------
// C[M,N] = act(A[M,K](bf16) @ B[K,N](bf16) + bias(f32)), row-major.
// OUTF32=0 -> C bf16, OUTF32=1 -> C f32.
// 128x128 tile, 256 threads = 4 waves (2x2), each wave 64x64 (4x4 frags 16x16).
// K-step 32, double-buffered LDS. M,N mult of 128, K mult of 32.
template <int ACT, int BIAS, int OUTF32>
__global__ __launch_bounds__(256) void bgemm(const unsigned short* __restrict__ A,
                                             const unsigned short* __restrict__ B,
                                             const float* __restrict__ bias,
                                             void* __restrict__ Cv,
                                             int M, int N, int K,
                                             int lda, int ldb, int ldc) {
    __shared__ unsigned short Abuf[2][4][128][8];
    __shared__ unsigned short Bbuf[2][4][128][8];
    int tid = threadIdx.x;
    int bm = blockIdx.y * 128, bn = blockIdx.x * 128;
    int wid = tid >> 6, lane = tid & 63;
    int wr = wid >> 1, wc = wid & 1;

    int arow = tid >> 1, ahalf = tid & 1;      // A staging
    int bcol = (tid & 63) * 2, bkb = tid >> 6; // B staging (col pair, kblock)

    f32x4 acc[4][4] = {};
    uint4 areg0, areg1;
    unsigned br0[4], br1[4];

    const int nt = K / 32;

    auto gload = [&](int t) {
        int k0 = t * 32;
        const unsigned short* ap = A + (size_t)(bm + arow) * lda + k0 + ahalf * 16;
        areg0 = *(const uint4*)(ap);
        areg1 = *(const uint4*)(ap + 8);
        const unsigned short* bp = B + (size_t)(k0 + bkb * 8) * ldb + bn + bcol;
#pragma unroll
        for (int jj = 0; jj < 4; ++jj) {
            unsigned lo = *(const unsigned*)(bp);            // k = 2jj
            unsigned hi = *(const unsigned*)(bp + ldb);      // k = 2jj+1
            br0[jj] = (lo & 0xffffu) | (hi << 16);
            br1[jj] = (lo >> 16) | (hi & 0xffff0000u);
            bp += 2 * (size_t)ldb;
        }
    };
    auto swrite = [&](int buf) {
        *(uint4*)(&Abuf[buf][ahalf * 2 + 0][arow][0]) = areg0;
        *(uint4*)(&Abuf[buf][ahalf * 2 + 1][arow][0]) = areg1;
        *(uint4*)(&Bbuf[buf][bkb][bcol][0]) = *(uint4*)br0;
        *(uint4*)(&Bbuf[buf][bkb][bcol + 1][0]) = *(uint4*)br1;
    };

    gload(0);
    swrite(0);
    __syncthreads();
    for (int t = 0; t < nt; ++t) {
        if (t + 1 < nt) gload(t + 1);
        int buf = t & 1;
        int kb = lane >> 4, lr = lane & 15;
        short8 af[4], bfr[4];
#pragma unroll
        for (int i = 0; i < 4; ++i)
            af[i] = *(const short8*)(&Abuf[buf][kb][wr * 64 + i * 16 + lr][0]);
#pragma unroll
        for (int j = 0; j < 4; ++j)
            bfr[j] = *(const short8*)(&Bbuf[buf][kb][wc * 64 + j * 16 + lr][0]);
#pragma unroll
        for (int i = 0; i < 4; ++i)
#pragma unroll
            for (int j = 0; j < 4; ++j)
                acc[i][j] = __builtin_amdgcn_mfma_f32_16x16x32_bf16(
                    af[i], bfr[j], acc[i][j], 0, 0, 0);
        if (t + 1 < nt) swrite(buf ^ 1);
        __syncthreads();
    }
    // epilogue: C/D layout col=lane&15, row=(lane>>4)*4+reg
    int lr = lane & 15, rg = lane >> 4;
#pragma unroll
    for (int j = 0; j < 4; ++j) {
        int col = bn + wc * 64 + j * 16 + lr;
        float bv = BIAS ? bias[col] : 0.f;
#pragma unroll
        for (int i = 0; i < 4; ++i) {
            int row0 = bm + wr * 64 + i * 16 + rg * 4;
#pragma unroll
            for (int r = 0; r < 4; ++r) {
                float v = acc[i][j][r] + bv;
                if (ACT) v = fmaxf(v, 0.f);
                if (OUTF32)
                    ((float*)Cv)[(size_t)(row0 + r) * ldc + col] = v;
                else
                    ((unsigned short*)Cv)[(size_t)(row0 + r) * ldc + col] = f2bf(v);
            }
        }
    }
}

// ---------------- layer-3 pruned row-gather (bf16 in, bf16 out) ----------------
__global__ void k_y(const float* __restrict__ An, const int* __restrict__ gsid,
                    const unsigned short* __restrict__ X2, unsigned short* __restrict__ y,
                    int b0, int Bc) {
    int bi = blockIdx.x, t = threadIdx.x;   // 256 threads, 2 channels each
    int b = b0 + bi;
    int g = gsid[b];
    float a0 = 0.f, a1 = 0.f;
    for (int m = 0; m < N_; ++m) {
        float a = An[g * N_ + m];   // broadcast
        if (a == 0.f) continue;     // uniform skip (~90%)
        const unsigned short* row = X2 + ((size_t)m * Bc + bi) * H1;
        a0 += a * bf2f(row[t]);
        a1 += a * bf2f(row[t + 256]);
    }
    y[(size_t)b * H1 + t] = f2bf(a0);
    y[(size_t)b * H1 + t + 256] = f2bf(a1);
}

// ---------------- BatchNorm training stats ----------------
__global__ void k_bnstats(const float* __restrict__ h, float* __restrict__ mv) {
    int c = blockIdx.x * 64 + threadIdx.x;   // 512 channels
    float s = 0.f, s2 = 0.f;
    for (int b = 0; b < B_; ++b) {
        float v = h[(size_t)b * FCH + c];
        s += v; s2 += v * v;
    }
    float mean = s * (1.f / B_);
    float var = s2 * (1.f / B_) - mean * mean;
    mv[c] = mean;
    mv[FCH + c] = rsqrtf(var + 1e-5f);
}

// ---------------- BN + LeakyReLU + final Linear + sigmoid ----------------
__global__ void k_head(const float* __restrict__ h, const float* __restrict__ mv,
                       const float* __restrict__ gamma, const float* __restrict__ beta,
                       const float* __restrict__ fcW2, const float* __restrict__ fcb2,
                       float* __restrict__ out) {
    int b = blockIdx.x, t = threadIdx.x;   // 512 threads
    float v = h[(size_t)b * FCH + t];
    v = (v - mv[t]) * mv[FCH + t] * gamma[t] + beta[t];
    v = (v >= 0.f) ? v : 0.01f * v;
    float p = v * fcW2[t];
    __shared__ float red[8];
    for (int off = 32; off; off >>= 1) p += __shfl_down(p, off);
    if ((t & 63) == 0) red[t >> 6] = p;
    __syncthreads();
    if (t == 0) {
        float s = fcb2[0];
#pragma unroll
        for (int i = 0; i < 8; ++i) s += red[i];
        out[b] = 1.f / (1.f + expf(-s));
    }
}

static inline size_t align256(size_t x) { return (x + 255) & ~(size_t)255; }

extern "C" void kernel_launch(void* const* d_in, const int* in_sizes, int n_in,
                              void* d_out, int out_size, void* d_ws, size_t ws_size,
                              hipStream_t stream) {
    const float* x     = (const float*)d_in[0];
    const float* adj   = (const float*)d_in[1];
    const float* W1    = (const float*)d_in[2];
    const float* b1    = (const float*)d_in[3];
    const float* W2    = (const float*)d_in[4];
    const float* b2    = (const float*)d_in[5];
    const float* W3    = (const float*)d_in[6];
    const float* b3    = (const float*)d_in[7];
    const float* fcW1  = (const float*)d_in[8];
    const float* fcb1  = (const float*)d_in[9];
    const float* gamma = (const float*)d_in[10];
    const float* beta  = (const float*)d_in[11];
    const float* fcW2  = (const float*)d_in[12];
    const float* fcb2  = (const float*)d_in[13];
    float* out = (float*)d_out;

    // Fixed buffers
    size_t fixed = 0;
    fixed += align256((size_t)N_ * N_ * 4);        // An f32
    fixed += align256((size_t)N_ * N_ * 2);        // An bf16
    fixed += align256((size_t)N_ * 4);             // dinv
    fixed += align256((size_t)B_ * S_ * 4);        // sid
    fixed += align256((size_t)B_ * 4);             // gsid
    fixed += align256((size_t)64 * H1 * 2);        // W1b
    fixed += align256((size_t)H1 * H1 * 2);        // W2b
    fixed += align256((size_t)H1 * H2 * 2);        // W3b
    fixed += align256((size_t)H2 * FCH * 2);       // fcW1b
    fixed += align256((size_t)B_ * H1 * 2);        // y (bf16)
    fixed += align256((size_t)B_ * H2 * 2);        // g (bf16)
    fixed += align256((size_t)B_ * FCH * 4);       // h (f32)
    fixed += align256((size_t)1024 * 4);           // mv

    // chunk buffers: 2 x (N * Bc * H1 bf16)
    int Bc = 0;
    for (int c : {256, 128, 64, 32, 16, 8, 4, 2}) {
        size_t need = fixed + 2 * align256((size_t)N_ * c * H1 * 2);
        if (need <= ws_size) { Bc = c; break; }
    }
    if (Bc == 0) return;

    char* ws = (char*)d_ws;
    size_t off = 0;
    auto alloc = [&](size_t bytes) { char* p = ws + off; off += align256(bytes); return p; };
    float*          An    = (float*)alloc((size_t)N_ * N_ * 4);
    unsigned short* Anb   = (unsigned short*)alloc((size_t)N_ * N_ * 2);
    float*          dinv  = (float*)alloc((size_t)N_ * 4);
    int*            sid   = (int*)alloc((size_t)B_ * S_ * 4);
    int*            gsid  = (int*)alloc((size_t)B_ * 4);
    unsigned short* W1b   = (unsigned short*)alloc((size_t)64 * H1 * 2);
    unsigned short* W2b   = (unsigned short*)alloc((size_t)H1 * H1 * 2);
    unsigned short* W3b   = (unsigned short*)alloc((size_t)H1 * H2 * 2);
    unsigned short* fcW1b = (unsigned short*)alloc((size_t)H2 * FCH * 2);
    unsigned short* y     = (unsigned short*)alloc((size_t)B_ * H1 * 2);
    unsigned short* g     = (unsigned short*)alloc((size_t)B_ * H2 * 2);
    float*          h     = (float*)alloc((size_t)B_ * FCH * 4);
    float*          mv    = (float*)alloc((size_t)1024 * 4);
    unsigned short* bufP  = (unsigned short*)alloc((size_t)N_ * Bc * H1 * 2); // Xs, X1, X2
    unsigned short* bufQ  = (unsigned short*)alloc((size_t)N_ * Bc * H1 * 2); // T0, T1

    k_dinv<<<N_, 64, 0, stream>>>(adj, dinv);
    k_an<<<N_, 256, 0, stream>>>(adj, dinv, An, Anb);
    k_sid<<<(B_ * S_) / 256, 256, 0, stream>>>(x, sid, gsid);
    k_cvt<<<(64 * H1) / 256, 256, 0, stream>>>(W1, W1b, Fm1 * H1, 64 * H1);
    k_cvt<<<(H1 * H1) / 256, 256, 0, stream>>>(W2, W2b, H1 * H1, H1 * H1);
    k_cvt<<<(H1 * H2) / 256, 256, 0, stream>>>(W3, W3b, H1 * H2, H1 * H2);
    k_cvt<<<(H2 * FCH) / 256, 256, 0, stream>>>(fcW1, fcW1b, H2 * FCH, H2 * FCH);

    for (int b0 = 0; b0 < B_; b0 += Bc) {
        // zero + scatter Xs[m][bi][64] (bf16) into bufP
        int n16 = (N_ * Bc * 64) / 8;
        k_zero<<<(n16 + 255) / 256, 256, 0, stream>>>((uint4*)bufP, n16);
        k_scatter<<<(Bc * S_ * 8) / 256, 256, 0, stream>>>(x, sid, bufP, b0, Bc);

        // GEMM0: T0 = An @ Xs          M=256, N=Bc*64, K=256
        bgemm<0, 0, 0><<<dim3((Bc * 64) / 128, 2), 256, 0, stream>>>(
            Anb, bufP, nullptr, bufQ, N_, Bc * 64, N_, N_, Bc * 64, Bc * 64);

        // GEMM1: X1 = relu(T0 @ W1 + b1)   M=N*Bc, N=512, K=64 (padded)
        bgemm<1, 1, 0><<<dim3(H1 / 128, (N_ * Bc) / 128), 256, 0, stream>>>(
            bufQ, W1b, b1, bufP, N_ * Bc, H1, 64, 64, H1, H1);

        // GEMM2: T1 = An @ X1          M=256, N=Bc*512, K=256
        bgemm<0, 0, 0><<<dim3((Bc * H1) / 128, 2), 256, 0, stream>>>(
            Anb, bufP, nullptr, bufQ, N_, Bc * H1, N_, N_, Bc * H1, Bc * H1);

        // GEMM3: X2 = relu(T1 @ W2 + b2)   M=N*Bc, N=512, K=512
        bgemm<1, 1, 0><<<dim3(H1 / 128, (N_ * Bc) / 128), 256, 0, stream>>>(
            bufQ, W2b, b2, bufP, N_ * Bc, H1, H1, H1, H1, H1);

        // y[b,h] = An[gsid[b],:] @ X2[:,bi,h]   (bf16 out)
        k_y<<<Bc, 256, 0, stream>>>(An, gsid, bufP, y, b0, Bc);
    }

    // GEMM4: g = relu(y @ W3 + b3)   256 x 1024 x 512 (bf16 out)
    bgemm<1, 1, 0><<<dim3(H2 / 128, B_ / 128), 256, 0, stream>>>(
        y, W3b, b3, g, B_, H2, H1, H1, H2, H2);

    // GEMM5: h = g @ fcW1 + fcb1     256 x 512 x 1024 (f32 out)
    bgemm<0, 1, 1><<<dim3(FCH / 128, B_ / 128), 256, 0, stream>>>(
        g, fcW1b, fcb1, h, B_, FCH, H2, H2, FCH, FCH);

    k_bnstats<<<FCH / 64, 64, 0, stream>>>(h, mv);
    k_head<<<B_, FCH, 0, stream>>>(h, mv, gamma, beta, fcW2, fcb2, out);
}

// Round 5
// 232.459 us; speedup vs baseline: 22.6315x; 1.0058x over previous
//
#include <hip/hip_runtime.h>
#include <cstdint>
#include <initializer_list>

// Problem constants
#define B_   256   // BATCH
#define N_   256   // NODE_NUM
#define S_   128   // SEQ_LEN
#define Fm1  63    // FEATURE_NUM-1
#define XROW 65    // FEATURE_NUM+1 (x last-dim)
#define H1   512   // HIDDEN/2
#define H2   1024  // HIDDEN
#define FCH  512   // FC_HIDDEN

typedef __attribute__((ext_vector_type(8))) short short8;
typedef __attribute__((ext_vector_type(4))) float f32x4;

__device__ __forceinline__ unsigned short f2bf(float f) {
    union { float f; unsigned u; } v; v.f = f;
    unsigned r = v.u + 0x7FFF + ((v.u >> 16) & 1);   // RNE
    return (unsigned short)(r >> 16);
}
__device__ __forceinline__ float bf2f(unsigned short u) {
    union { unsigned u; float f; } v; v.u = ((unsigned)u) << 16;
    return v.f;
}

// ---------------- adjacency normalization ----------------
__global__ void k_dinv(const float* __restrict__ adj, float* __restrict__ dinv) {
    int n = blockIdx.x;
    float s = 0.f;
    for (int m = threadIdx.x; m < N_; m += 64) s += adj[n * N_ + m];
    for (int off = 32; off; off >>= 1) s += __shfl_down(s, off);
    if (threadIdx.x == 0) dinv[n] = rsqrtf(s + 1.0f);
}

__global__ void k_an(const float* __restrict__ adj, const float* __restrict__ dinv,
                     float* __restrict__ An, unsigned short* __restrict__ Anb) {
    int i = blockIdx.x * 256 + threadIdx.x;
    int n = i >> 8, m = i & 255;
    float a = adj[i] + (n == m ? 1.f : 0.f);
    float v = a * dinv[n] * dinv[m];
    An[i] = v;
    Anb[i] = f2bf(v);
}

// ---------------- station-id extraction ----------------
__global__ void k_sid(const float* __restrict__ x, int* __restrict__ sid,
                      int* __restrict__ gsid) {
    int i = blockIdx.x * 256 + threadIdx.x;   // 32768 = B*S
    int b = i >> 7, j = i & 127;
    int s = (int)x[(size_t)b * (S_ * XROW) + j * XROW + (XROW - 2)];
    sid[i] = s;
    if (j == S_ - 1) gsid[b] = s;
}

// ---------------- fp32 transpose -> bf16, zero-pad rows >= R_in ----------------
// out[c][r] (C_in x R_pad) = in[r][c] (R_in x C_in), bf16
__global__ void k_cvtT(const float* __restrict__ in, unsigned short* __restrict__ out,
                       int R_in, int C_in, int R_pad) {
    __shared__ float tile[32][33];
    int r0 = blockIdx.y * 32, c0 = blockIdx.x * 32;
    int tr = threadIdx.x >> 5, tc = threadIdx.x & 31;   // 8 x 32
#pragma unroll
    for (int rr = 0; rr < 4; ++rr) {
        int r = r0 + tr + rr * 8;
        tile[tr + rr * 8][tc] = (r < R_in) ? in[(size_t)r * C_in + c0 + tc] : 0.f;
    }
    __syncthreads();
#pragma unroll
    for (int rr = 0; rr < 4; ++rr) {
        int c = c0 + tr + rr * 8;
        int r = r0 + tc;
        out[(size_t)c * R_pad + r] = f2bf(tile[tc][tr + rr * 8]);
    }
}

// ---------------- zero fill (16B granules) ----------------
__global__ void k_zero(uint4* __restrict__ p, int n16) {
    int i = blockIdx.x * 256 + threadIdx.x;
    if (i < n16) p[i] = uint4{0, 0, 0, 0};
}

// ---------------- scatter x -> node-major bf16 Xs[m][bi][64] ----------------
__global__ void k_scatter(const float* __restrict__ x, const int* __restrict__ sid,
                          unsigned short* __restrict__ Xs, int b0, int Bc) {
    int idx = blockIdx.x * 256 + threadIdx.x;    // Bc*S*8 threads
    int f8 = idx & 7;
    int j  = (idx >> 3) & 127;
    int bi = idx >> 10;
    int gb = b0 + bi;
    int s = sid[gb * S_ + j];
    const float* src = x + ((size_t)gb * S_ + j) * XROW + f8 * 8;
    unsigned short o[8];
#pragma unroll
    for (int i = 0; i < 8; ++i) {
        int f = f8 * 8 + i;
        o[i] = (f < Fm1) ? f2bf(src[i]) : (unsigned short)0;
    }
    *(uint4*)(Xs + ((size_t)s * Bc + bi) * 64 + f8 * 8) = *(uint4*)o;
}

// ---------------- packing bgemm (GEMM0 only: B row-major [K,N]) ----------------
template <int ACT, int BIAS>
__global__ __launch_bounds__(256) void bgemm(const unsigned short* __restrict__ A,
                                             const unsigned short* __restrict__ B,
                                             const float* __restrict__ bias,
                                             unsigned short* __restrict__ C,
                                             int K, int lda, int ldb, int ldc) {
    __shared__ unsigned short Abuf[2][4][128][8];
    __shared__ unsigned short Bbuf[2][4][128][8];
    int tid = threadIdx.x;
    int bm = blockIdx.y * 128, bn = blockIdx.x * 128;
    int wid = tid >> 6, lane = tid & 63;
    int wr = wid >> 1, wc = wid & 1;
    int arow = tid >> 1, ahalf = tid & 1;
    int bcol = (tid & 63) * 2, bkb = tid >> 6;
    f32x4 acc[4][4] = {};
    uint4 areg0, areg1;
    unsigned br0[4], br1[4];
    const int nt = K / 32;
    auto gload = [&](int t) {
        int k0 = t * 32;
        const unsigned short* ap = A + (size_t)(bm + arow) * lda + k0 + ahalf * 16;
        areg0 = *(const uint4*)(ap);
        areg1 = *(const uint4*)(ap + 8);
        const unsigned short* bp = B + (size_t)(k0 + bkb * 8) * ldb + bn + bcol;
#pragma unroll
        for (int jj = 0; jj < 4; ++jj) {
            unsigned lo = *(const unsigned*)(bp);
            unsigned hi = *(const unsigned*)(bp + ldb);
            br0[jj] = (lo & 0xffffu) | (hi << 16);
            br1[jj] = (lo >> 16) | (hi & 0xffff0000u);
            bp += 2 * (size_t)ldb;
        }
    };
    auto swrite = [&](int buf) {
        *(uint4*)(&Abuf[buf][ahalf * 2 + 0][arow][0]) = areg0;
        *(uint4*)(&Abuf[buf][ahalf * 2 + 1][arow][0]) = areg1;
        *(uint4*)(&Bbuf[buf][bkb][bcol][0]) = *(uint4*)br0;
        *(uint4*)(&Bbuf[buf][bkb][bcol + 1][0]) = *(uint4*)br1;
    };
    gload(0);
    swrite(0);
    __syncthreads();
    for (int t = 0; t < nt; ++t) {
        if (t + 1 < nt) gload(t + 1);
        int buf = t & 1;
        int kb = lane >> 4, lr = lane & 15;
        short8 af[4], bfr[4];
#pragma unroll
        for (int i = 0; i < 4; ++i)
            af[i] = *(const short8*)(&Abuf[buf][kb][wr * 64 + i * 16 + lr][0]);
#pragma unroll
        for (int j = 0; j < 4; ++j)
            bfr[j] = *(const short8*)(&Bbuf[buf][kb][wc * 64 + j * 16 + lr][0]);
#pragma unroll
        for (int i = 0; i < 4; ++i)
#pragma unroll
            for (int j = 0; j < 4; ++j)
                acc[i][j] = __builtin_amdgcn_mfma_f32_16x16x32_bf16(
                    af[i], bfr[j], acc[i][j], 0, 0, 0);
        if (t + 1 < nt) swrite(buf ^ 1);
        __syncthreads();
    }
    int lr = lane & 15, rg = lane >> 4;
#pragma unroll
    for (int j = 0; j < 4; ++j) {
        int col = bn + wc * 64 + j * 16 + lr;
        float bv = BIAS ? bias[col] : 0.f;
#pragma unroll
        for (int i = 0; i < 4; ++i) {
            int row0 = bm + wr * 64 + i * 16 + rg * 4;
#pragma unroll
            for (int r = 0; r < 4; ++r) {
                float v = acc[i][j][r] + bv;
                if (ACT) v = fmaxf(v, 0.f);
                C[(size_t)(row0 + r) * ldc + col] = f2bf(v);
            }
        }
    }
}

// ---------------- bt-GEMM (m97 structure): C = act(A @ B^T + bias) ----------------
// A[M,K] row-major (lda), B stored [N,K] row-major (ldb) -> both K-contiguous.
// 128x128 tile, 4 waves, K-step 32, global_load_lds(16B) staging, double-buffered.
// Batched via blockIdx.x: sample = bx>>ns, bn = (bx & mask)*128; B/C offset by
// sample*sb / sample*sc. BIASMODE: 0 none, 1 per-col, 2 per-row.
template <int ACT, int BIASMODE, int OUTF32>
__global__ __launch_bounds__(256) void btgemm(const unsigned short* __restrict__ A,
                                              const unsigned short* __restrict__ Bm,
                                              const float* __restrict__ bias,
                                              void* __restrict__ Cv,
                                              int K, int lda, int ldb, int ldc,
                                              int ns, int sb, int sc) {
    __shared__ unsigned short Ab[2][128][32];
    __shared__ unsigned short Bb[2][128][32];
    int tid = threadIdx.x;
    int bm = blockIdx.y * 128;
    int bx = blockIdx.x;
    int sample = bx >> ns;
    int bn = (bx & ((1 << ns) - 1)) * 128;
    const unsigned short* Bp = Bm + (size_t)sample * sb;
    size_t coff = (size_t)sample * sc;

    int wid = tid >> 6, lane = tid & 63;
    int wr = wid >> 1, wc = wid & 1;
    int c0 = wid * 2;                  // wave's 16-row chunk pair
    int lrow = lane >> 2, lkq = lane & 3;

    f32x4 acc[4][4] = {};
    const int nt = K / 32;

    auto STAGE = [&](int t, int buf) {
        int k0 = t * 32;
#pragma unroll
        for (int i = 0; i < 2; ++i) {
            int row = (c0 + i) * 16 + lrow;
            const unsigned short* ga = A + (size_t)(bm + row) * lda + k0 + lkq * 8;
            __builtin_amdgcn_global_load_lds(
                (const __attribute__((address_space(1))) unsigned int*)ga,
                (__attribute__((address_space(3))) unsigned int*)&Ab[buf][(c0 + i) * 16][0],
                16, 0, 0);
            const unsigned short* gb = Bp + (size_t)(bn + row) * ldb + k0 + lkq * 8;
            __builtin_amdgcn_global_load_lds(
                (const __attribute__((address_space(1))) unsigned int*)gb,
                (__attribute__((address_space(3))) unsigned int*)&Bb[buf][(c0 + i) * 16][0],
                16, 0, 0);
        }
    };

    STAGE(0, 0);
    __syncthreads();
    int kb = lane >> 4, lr = lane & 15;
    for (int t = 0; t < nt; ++t) {
        int buf = t & 1;
        if (t + 1 < nt) STAGE(t + 1, buf ^ 1);
        short8 af[4], bfr[4];
#pragma unroll
        for (int i = 0; i < 4; ++i)
            af[i] = *(const short8*)&Ab[buf][wr * 64 + i * 16 + lr][kb * 8];
#pragma unroll
        for (int j = 0; j < 4; ++j)
            bfr[j] = *(const short8*)&Bb[buf][wc * 64 + j * 16 + lr][kb * 8];
#pragma unroll
        for (int i = 0; i < 4; ++i)
#pragma unroll
            for (int j = 0; j < 4; ++j)
                acc[i][j] = __builtin_amdgcn_mfma_f32_16x16x32_bf16(
                    af[i], bfr[j], acc[i][j], 0, 0, 0);
        __syncthreads();
    }
    // epilogue: C/D layout col=lane&15, row=(lane>>4)*4+reg
    int rg = lane >> 4;
#pragma unroll
    for (int j = 0; j < 4; ++j) {
        int col = bn + wc * 64 + j * 16 + lr;
        float bcv = (BIASMODE == 1) ? bias[col] : 0.f;
#pragma unroll
        for (int i = 0; i < 4; ++i) {
            int row0 = bm + wr * 64 + i * 16 + rg * 4;
#pragma unroll
            for (int r = 0; r < 4; ++r) {
                float v = acc[i][j][r];
                if (BIASMODE == 1) v += bcv;
                if (BIASMODE == 2) v += bias[row0 + r];
                if (ACT) v = fmaxf(v, 0.f);
                if (OUTF32)
                    ((float*)Cv)[coff + (size_t)(row0 + r) * ldc + col] = v;
                else
                    ((unsigned short*)Cv)[coff + (size_t)(row0 + r) * ldc + col] = f2bf(v);
            }
        }
    }
}

// ---------------- layer-3 pruned row-gather (bf16 in, bf16 out) ----------------
__global__ void k_y(const float* __restrict__ An, const int* __restrict__ gsid,
                    const unsigned short* __restrict__ X2, unsigned short* __restrict__ y,
                    int b0, int Bc) {
    int bi = blockIdx.x, t = threadIdx.x;
    int b = b0 + bi;
    int g = gsid[b];
    float a0 = 0.f, a1 = 0.f;
    for (int m = 0; m < N_; ++m) {
        float a = An[g * N_ + m];
        if (a == 0.f) continue;
        const unsigned short* row = X2 + ((size_t)m * Bc + bi) * H1;
        a0 += a * bf2f(row[t]);
        a1 += a * bf2f(row[t + 256]);
    }
    y[(size_t)b * H1 + t] = f2bf(a0);
    y[(size_t)b * H1 + t + 256] = f2bf(a1);
}

// ---------------- BatchNorm training stats ----------------
__global__ void k_bnstats(const float* __restrict__ h, float* __restrict__ mv) {
    int c = blockIdx.x * 64 + threadIdx.x;
    float s = 0.f, s2 = 0.f;
    for (int b = 0; b < B_; ++b) {
        float v = h[(size_t)b * FCH + c];
        s += v; s2 += v * v;
    }
    float mean = s * (1.f / B_);
    float var = s2 * (1.f / B_) - mean * mean;
    mv[c] = mean;
    mv[FCH + c] = rsqrtf(var + 1e-5f);
}

// ---------------- BN + LeakyReLU + final Linear + sigmoid ----------------
__global__ void k_head(const float* __restrict__ h, const float* __restrict__ mv,
                       const float* __restrict__ gamma, const float* __restrict__ beta,
                       const float* __restrict__ fcW2, const float* __restrict__ fcb2,
                       float* __restrict__ out) {
    int b = blockIdx.x, t = threadIdx.x;
    float v = h[(size_t)b * FCH + t];
    v = (v - mv[t]) * mv[FCH + t] * gamma[t] + beta[t];
    v = (v >= 0.f) ? v : 0.01f * v;
    float p = v * fcW2[t];
    __shared__ float red[8];
    for (int off = 32; off; off >>= 1) p += __shfl_down(p, off);
    if ((t & 63) == 0) red[t >> 6] = p;
    __syncthreads();
    if (t == 0) {
        float s = fcb2[0];
#pragma unroll
        for (int i = 0; i < 8; ++i) s += red[i];
        out[b] = 1.f / (1.f + expf(-s));
    }
}

static inline size_t align256(size_t x) { return (x + 255) & ~(size_t)255; }

extern "C" void kernel_launch(void* const* d_in, const int* in_sizes, int n_in,
                              void* d_out, int out_size, void* d_ws, size_t ws_size,
                              hipStream_t stream) {
    const float* x     = (const float*)d_in[0];
    const float* adj   = (const float*)d_in[1];
    const float* W1    = (const float*)d_in[2];
    const float* b1    = (const float*)d_in[3];
    const float* W2    = (const float*)d_in[4];
    const float* b2    = (const float*)d_in[5];
    const float* W3    = (const float*)d_in[6];
    const float* b3    = (const float*)d_in[7];
    const float* fcW1  = (const float*)d_in[8];
    const float* fcb1  = (const float*)d_in[9];
    const float* gamma = (const float*)d_in[10];
    const float* beta  = (const float*)d_in[11];
    const float* fcW2  = (const float*)d_in[12];
    const float* fcb2  = (const float*)d_in[13];
    float* out = (float*)d_out;

    size_t fixed = 0;
    fixed += align256((size_t)N_ * N_ * 4);        // An f32
    fixed += align256((size_t)N_ * N_ * 2);        // Anb
    fixed += align256((size_t)N_ * 4);             // dinv
    fixed += align256((size_t)B_ * S_ * 4);        // sid
    fixed += align256((size_t)B_ * 4);             // gsid
    fixed += align256((size_t)H1 * 64 * 2);        // W1T  [512][64]
    fixed += align256((size_t)H1 * H1 * 2);        // W2T  [512][512]
    fixed += align256((size_t)H2 * H1 * 2);        // W3T  [1024][512]
    fixed += align256((size_t)H1 * H2 * 2);        // fcW1T[512][1024]
    fixed += align256((size_t)B_ * H1 * 2);        // y bf16
    fixed += align256((size_t)B_ * H2 * 2);        // g bf16
    fixed += align256((size_t)B_ * FCH * 4);       // h f32
    fixed += align256((size_t)1024 * 4);           // mv

    auto chunk_bytes = [&](int c) {
        return 2 * align256((size_t)N_ * c * 64 * 2) +   // Xs, T0
               2 * align256((size_t)N_ * c * H1 * 2);    // X1n(/X2), T1
    };
    int Bc = 0;
    for (int c : {256, 128, 64, 32, 16, 8}) {
        if (fixed + chunk_bytes(c) <= ws_size) { Bc = c; break; }
    }
    if (Bc == 0) return;

    char* ws = (char*)d_ws;
    size_t off = 0;
    auto alloc = [&](size_t bytes) { char* p = ws + off; off += align256(bytes); return p; };
    float*          An    = (float*)alloc((size_t)N_ * N_ * 4);
    unsigned short* Anb   = (unsigned short*)alloc((size_t)N_ * N_ * 2);
    float*          dinv  = (float*)alloc((size_t)N_ * 4);
    int*            sid   = (int*)alloc((size_t)B_ * S_ * 4);
    int*            gsid  = (int*)alloc((size_t)B_ * 4);
    unsigned short* W1T   = (unsigned short*)alloc((size_t)H1 * 64 * 2);
    unsigned short* W2T   = (unsigned short*)alloc((size_t)H1 * H1 * 2);
    unsigned short* W3T   = (unsigned short*)alloc((size_t)H2 * H1 * 2);
    unsigned short* fcW1T = (unsigned short*)alloc((size_t)H1 * H2 * 2);
    unsigned short* y     = (unsigned short*)alloc((size_t)B_ * H1 * 2);
    unsigned short* g     = (unsigned short*)alloc((size_t)B_ * H2 * 2);
    float*          h     = (float*)alloc((size_t)B_ * FCH * 4);
    float*          mv    = (float*)alloc((size_t)1024 * 4);
    unsigned short* Xs    = (unsigned short*)alloc((size_t)N_ * Bc * 64 * 2);
    unsigned short* T0    = (unsigned short*)alloc((size_t)N_ * Bc * 64 * 2);
    unsigned short* X1n   = (unsigned short*)alloc((size_t)N_ * Bc * H1 * 2); // also X2
    unsigned short* T1    = (unsigned short*)alloc((size_t)N_ * Bc * H1 * 2);

    k_dinv<<<N_, 64, 0, stream>>>(adj, dinv);
    k_an<<<N_, 256, 0, stream>>>(adj, dinv, An, Anb);
    k_sid<<<(B_ * S_) / 256, 256, 0, stream>>>(x, sid, gsid);
    // weight transposes (bf16): W1T[h][f(pad64)], W2T[h'][h], W3T[q][h], fcW1T[c][q]
    k_cvtT<<<dim3(H1 / 32, 64 / 32), 256, 0, stream>>>(W1, W1T, Fm1, H1, 64);
    k_cvtT<<<dim3(H1 / 32, H1 / 32), 256, 0, stream>>>(W2, W2T, H1, H1, H1);
    k_cvtT<<<dim3(H2 / 32, H1 / 32), 256, 0, stream>>>(W3, W3T, H1, H2, H1);
    k_cvtT<<<dim3(H1 / 32, H2 / 32), 256, 0, stream>>>(fcW1, fcW1T, H2, H1, H2);

    for (int b0 = 0; b0 < B_; b0 += Bc) {
        int n16 = (N_ * Bc * 64) / 8;
        k_zero<<<(n16 + 255) / 256, 256, 0, stream>>>((uint4*)Xs, n16);
        k_scatter<<<(Bc * S_ * 8) / 256, 256, 0, stream>>>(x, sid, Xs, b0, Bc);

        // GEMM0 (packing kernel): T0[n][(b,f)] = An @ Xs   M=256, N=Bc*64, K=256
        bgemm<0, 0><<<dim3((Bc * 64) / 128, 2), 256, 0, stream>>>(
            Anb, Xs, nullptr, T0, N_, N_, Bc * 64, Bc * 64);

        // GEMM1 (batched bt): X1n[b][h][m] = relu(W1T @ T0_b^T + b1[h])
        //   per-sample M=512 (h), N=256 (m), K=64
        btgemm<1, 2, 0><<<dim3(2 * Bc, H1 / 128), 256, 0, stream>>>(
            W1T, T0, b1, X1n, 64, 64, Bc * 64, N_,
            1, 64, H1 * N_);

        // GEMM2 (bt): T1[n][(b,h)] = An @ X1n^T   M=256, N=Bc*512, K=256
        btgemm<0, 0, 0><<<dim3((Bc * H1) / 128, 2), 256, 0, stream>>>(
            Anb, X1n, nullptr, T1, N_, N_, N_, Bc * H1,
            20, 0, 0);

        // GEMM3 (bt): X2[(n,b)][h'] = relu(T1 @ W2T^T + b2)  M=N*Bc, N=512, K=512
        btgemm<1, 1, 0><<<dim3(H1 / 128, (N_ * Bc) / 128), 256, 0, stream>>>(
            T1, W2T, b2, X1n, H1, H1, H1, H1,
            20, 0, 0);

        // y[b,h] = An[gsid[b],:] @ X2[:,bi,h]
        k_y<<<Bc, 256, 0, stream>>>(An, gsid, X1n, y, b0, Bc);
    }

    // GEMM4 (bt): g[b][q] = relu(y @ W3T^T + b3)   M=256, N=1024, K=512
    btgemm<1, 1, 0><<<dim3(H2 / 128, B_ / 128), 256, 0, stream>>>(
        y, W3T, b3, g, H1, H1, H1, H2, 20, 0, 0);

    // GEMM5 (bt): h[b][c] = g @ fcW1T^T + fcb1     M=256, N=512, K=1024 (f32 out)
    btgemm<0, 1, 1><<<dim3(FCH / 128, B_ / 128), 256, 0, stream>>>(
        g, fcW1T, fcb1, h, H2, H2, H2, FCH, 20, 0, 0);

    k_bnstats<<<FCH / 64, 64, 0, stream>>>(h, mv);
    k_head<<<B_, FCH, 0, stream>>>(h, mv, gamma, beta, fcW2, fcb2, out);
}